// Round 1
// baseline (872.610 us; speedup 1.0000x reference)
//
#include <hip/hip_runtime.h>

// Problem constants (from reference): B=8, T=2048, C=1024, H=128
constexpr int kB = 8;
constexpr int kT = 2048;
constexpr int kC = 1024;
constexpr int kH = 128;
constexpr int kM = kB * kT;  // 16384 rows of x

// ---------------------------------------------------------------------------
// Kernel 1: fused QKV projection. C = x @ W for W in {Wq, Wk, Wv}.
// fp32 register-blocked GEMM. Tile: 128 rows x 64 cols, K-step 32.
// grid = (6, 128): x -> {col-tile 0..1} x {mat 0..2}, y -> row-tile.
// Each thread computes an 8x4 micro-tile (16x16 thread grid).
// ---------------------------------------------------------------------------
__global__ __launch_bounds__(256) void qkv_gemm(
    const float* __restrict__ x,
    const float* __restrict__ Wk,
    const float* __restrict__ Wq,
    const float* __restrict__ Wv,
    float* __restrict__ ws)
{
    // As transposed [k][row] for conflict-free compute reads; +4 pad keeps
    // 16B alignment of rows (132*4 bytes) and breaks bank aliasing.
    __shared__ __align__(16) float As[32][132];
    __shared__ __align__(16) float Bs[32][68];

    const int nt  = blockIdx.x & 1;   // col tile (0..1)
    const int mat = blockIdx.x >> 1;  // 0=q, 1=k, 2=v
    const int mt  = blockIdx.y;       // row tile (0..127)

    const float* W = (mat == 0) ? Wq : (mat == 1) ? Wk : Wv;
    float* outp = ws + (size_t)mat * kM * kH;

    const int m0 = mt * 128;
    const int n0 = nt * 64;
    const int tid = threadIdx.x;
    const int tx = tid & 15;
    const int ty = tid >> 4;

    // A-load: 128 rows x 32 k, 2 threads/row, 4 float4 each
    const int alr = tid >> 1;
    const int alk = (tid & 1) * 16;
    // B-load: 32 k-rows x 64 cols, 8 threads/row, 2 float4 each
    const int bkk = tid >> 3;
    const int bc0 = (tid & 7) * 8;

    float acc[8][4];
#pragma unroll
    for (int i = 0; i < 8; ++i)
#pragma unroll
        for (int j = 0; j < 4; ++j) acc[i][j] = 0.0f;

    for (int kt = 0; kt < kC; kt += 32) {
        __syncthreads();
#pragma unroll
        for (int u = 0; u < 4; ++u) {
            const float4 av =
                *(const float4*)(x + (size_t)(m0 + alr) * kC + kt + alk + u * 4);
            As[alk + u * 4 + 0][alr] = av.x;
            As[alk + u * 4 + 1][alr] = av.y;
            As[alk + u * 4 + 2][alr] = av.z;
            As[alk + u * 4 + 3][alr] = av.w;
        }
#pragma unroll
        for (int u = 0; u < 2; ++u) {
            const float4 bv =
                *(const float4*)(W + (size_t)(kt + bkk) * kH + n0 + bc0 + u * 4);
            *(float4*)&Bs[bkk][bc0 + u * 4] = bv;
        }
        __syncthreads();
#pragma unroll
        for (int kk = 0; kk < 32; ++kk) {
            const float4 a0 = *(const float4*)&As[kk][ty * 8];
            const float4 a1 = *(const float4*)&As[kk][ty * 8 + 4];
            const float4 b0 = *(const float4*)&Bs[kk][tx * 4];
            const float a[8] = {a0.x, a0.y, a0.z, a0.w, a1.x, a1.y, a1.z, a1.w};
            const float bb[4] = {b0.x, b0.y, b0.z, b0.w};
#pragma unroll
            for (int i = 0; i < 8; ++i)
#pragma unroll
                for (int j = 0; j < 4; ++j)
                    acc[i][j] = fmaf(a[i], bb[j], acc[i][j]);
        }
    }

#pragma unroll
    for (int i = 0; i < 8; ++i) {
        const float4 o = make_float4(acc[i][0], acc[i][1], acc[i][2], acc[i][3]);
        *(float4*)(outp + (size_t)(m0 + ty * 8 + i) * kH + n0 + tx * 4) = o;
    }
}

// ---------------------------------------------------------------------------
// Kernel 2: flash-style causal attention, fp32.
// Block = one (batch, 32-row Q-tile). K/V-tiles of 64 rows share one LDS
// buffer. Online softmax; sqrt(C)=32 folded into Q at load. Thread (tx,ty)
// owns S rows ty*2+{0,1} x cols tx*4+{0..3}, and O rows ty*2+{0,1} x cols
// tx*8+{0..7}. Row reductions = shuffle-xor over lane bits 0..3 (= tx).
// ---------------------------------------------------------------------------
__global__ __launch_bounds__(256) void attn_fp32(
    const float* __restrict__ ws, float* __restrict__ out)
{
    __shared__ __align__(16) float Qs[32][132];
    __shared__ __align__(16) float KVs[64][132];
    __shared__ __align__(16) float Ps[32][68];

    const int idx = blockIdx.x;  // 0..511
    const int b = idx >> 6;
    const int ii = idx & 63;
    // causal work-balance swizzle: pair light tile with heavy tile
    const int qt = (ii & 1) ? (63 - (ii >> 1)) : (ii >> 1);
    const int i0 = qt * 32;

    const float* qp = ws + ((size_t)b * kT + i0) * kH;
    const float* kp = ws + (size_t)kM * kH + (size_t)b * kT * kH;
    const float* vp = ws + (size_t)2 * kM * kH + (size_t)b * kT * kH;

    const int tid = threadIdx.x;
    const int tx = tid & 15;
    const int ty = tid >> 4;

    // Load Q tile, scaled by sqrt(C)=32 (reference multiplies by C**0.5)
    {
        const int r = tid >> 3;
        const int h0 = (tid & 7) * 16;
#pragma unroll
        for (int u = 0; u < 4; ++u) {
            float4 qv = *(const float4*)(qp + (size_t)r * kH + h0 + u * 4);
            qv.x *= 32.0f; qv.y *= 32.0f; qv.z *= 32.0f; qv.w *= 32.0f;
            *(float4*)&Qs[r][h0 + u * 4] = qv;
        }
    }

    float o[2][8];
#pragma unroll
    for (int ri = 0; ri < 2; ++ri)
#pragma unroll
        for (int cc = 0; cc < 8; ++cc) o[ri][cc] = 0.0f;
    float m_old[2] = {-3.0e38f, -3.0e38f};
    float l[2] = {0.0f, 0.0f};

    const int jmax = qt >> 1;       // last 64-wide K tile index (causal)
    const int klr = tid >> 2;       // 0..63: K/V row loaded by this thread
    const int klh = (tid & 3) * 32; // 8 float4 per thread

    for (int j = 0; j <= jmax; ++j) {
        __syncthreads();  // protect KVs(V)/Ps readers of previous iteration
        // ---- load K tile [64 x 128] ----
#pragma unroll
        for (int u = 0; u < 8; ++u) {
            *(float4*)&KVs[klr][klh + u * 4] =
                *(const float4*)(kp + (size_t)(j * 64 + klr) * kH + klh + u * 4);
        }
        __syncthreads();

        // ---- S = Qs @ K^T  (rows ty*2+ri, cols tx*4+c) ----
        float s[2][4];
#pragma unroll
        for (int ri = 0; ri < 2; ++ri)
#pragma unroll
            for (int c = 0; c < 4; ++c) s[ri][c] = 0.0f;
#pragma unroll
        for (int h0 = 0; h0 < kH; h0 += 4) {
            const float4 q0 = *(const float4*)&Qs[ty * 2 + 0][h0];
            const float4 q1 = *(const float4*)&Qs[ty * 2 + 1][h0];
#pragma unroll
            for (int c = 0; c < 4; ++c) {
                const float4 kf = *(const float4*)&KVs[tx * 4 + c][h0];
                s[0][c] = fmaf(q0.x, kf.x, s[0][c]);
                s[0][c] = fmaf(q0.y, kf.y, s[0][c]);
                s[0][c] = fmaf(q0.z, kf.z, s[0][c]);
                s[0][c] = fmaf(q0.w, kf.w, s[0][c]);
                s[1][c] = fmaf(q1.x, kf.x, s[1][c]);
                s[1][c] = fmaf(q1.y, kf.y, s[1][c]);
                s[1][c] = fmaf(q1.z, kf.z, s[1][c]);
                s[1][c] = fmaf(q1.w, kf.w, s[1][c]);
            }
        }

        // ---- causal mask (only the diagonal tile needs it) ----
        if (j == jmax) {
#pragma unroll
            for (int ri = 0; ri < 2; ++ri) {
                const int grow = i0 + ty * 2 + ri;
#pragma unroll
                for (int c = 0; c < 4; ++c) {
                    const int gcol = j * 64 + tx * 4 + c;
                    if (gcol > grow) s[ri][c] = -3.0e38f;
                }
            }
        }

        // ---- online softmax update ----
        float alpha[2];
#pragma unroll
        for (int ri = 0; ri < 2; ++ri) {
            float mr = fmaxf(fmaxf(s[ri][0], s[ri][1]), fmaxf(s[ri][2], s[ri][3]));
            mr = fmaxf(mr, __shfl_xor(mr, 1));
            mr = fmaxf(mr, __shfl_xor(mr, 2));
            mr = fmaxf(mr, __shfl_xor(mr, 4));
            mr = fmaxf(mr, __shfl_xor(mr, 8));
            const float mn = fmaxf(m_old[ri], mr);
            alpha[ri] = expf(m_old[ri] - mn);
            float rs = 0.0f;
#pragma unroll
            for (int c = 0; c < 4; ++c) {
                s[ri][c] = expf(s[ri][c] - mn);
                rs += s[ri][c];
            }
            rs += __shfl_xor(rs, 1);
            rs += __shfl_xor(rs, 2);
            rs += __shfl_xor(rs, 4);
            rs += __shfl_xor(rs, 8);
            l[ri] = l[ri] * alpha[ri] + rs;
            m_old[ri] = mn;
        }

        // rescale O, publish P
#pragma unroll
        for (int ri = 0; ri < 2; ++ri) {
#pragma unroll
            for (int cc = 0; cc < 8; ++cc) o[ri][cc] *= alpha[ri];
            *(float4*)&Ps[ty * 2 + ri][tx * 4] =
                make_float4(s[ri][0], s[ri][1], s[ri][2], s[ri][3]);
        }

        __syncthreads();  // K reads done; P published
        // ---- load V tile over K ----
#pragma unroll
        for (int u = 0; u < 8; ++u) {
            *(float4*)&KVs[klr][klh + u * 4] =
                *(const float4*)(vp + (size_t)(j * 64 + klr) * kH + klh + u * 4);
        }
        __syncthreads();

        // ---- O += P @ V  (rows ty*2+ri, cols tx*8+cc) ----
#pragma unroll
        for (int jj = 0; jj < 64; jj += 4) {
            const float4 p0 = *(const float4*)&Ps[ty * 2 + 0][jj];
            const float4 p1 = *(const float4*)&Ps[ty * 2 + 1][jj];
            const float pa[4] = {p0.x, p0.y, p0.z, p0.w};
            const float pb[4] = {p1.x, p1.y, p1.z, p1.w};
#pragma unroll
            for (int u = 0; u < 4; ++u) {
                const float4 va = *(const float4*)&KVs[jj + u][tx * 8];
                const float4 vb = *(const float4*)&KVs[jj + u][tx * 8 + 4];
                o[0][0] = fmaf(pa[u], va.x, o[0][0]);
                o[0][1] = fmaf(pa[u], va.y, o[0][1]);
                o[0][2] = fmaf(pa[u], va.z, o[0][2]);
                o[0][3] = fmaf(pa[u], va.w, o[0][3]);
                o[0][4] = fmaf(pa[u], vb.x, o[0][4]);
                o[0][5] = fmaf(pa[u], vb.y, o[0][5]);
                o[0][6] = fmaf(pa[u], vb.z, o[0][6]);
                o[0][7] = fmaf(pa[u], vb.w, o[0][7]);
                o[1][0] = fmaf(pb[u], va.x, o[1][0]);
                o[1][1] = fmaf(pb[u], va.y, o[1][1]);
                o[1][2] = fmaf(pb[u], va.z, o[1][2]);
                o[1][3] = fmaf(pb[u], va.w, o[1][3]);
                o[1][4] = fmaf(pb[u], vb.x, o[1][4]);
                o[1][5] = fmaf(pb[u], vb.y, o[1][5]);
                o[1][6] = fmaf(pb[u], vb.z, o[1][6]);
                o[1][7] = fmaf(pb[u], vb.w, o[1][7]);
            }
        }
    }

    // ---- epilogue: O / l ----
#pragma unroll
    for (int ri = 0; ri < 2; ++ri) {
        const float inv = 1.0f / l[ri];
        float* op = out + ((size_t)b * kT + i0 + ty * 2 + ri) * kH + tx * 8;
        *(float4*)op = make_float4(o[ri][0] * inv, o[ri][1] * inv,
                                   o[ri][2] * inv, o[ri][3] * inv);
        *(float4*)(op + 4) = make_float4(o[ri][4] * inv, o[ri][5] * inv,
                                         o[ri][6] * inv, o[ri][7] * inv);
    }
}

// ---------------------------------------------------------------------------
extern "C" void kernel_launch(void* const* d_in, const int* in_sizes, int n_in,
                              void* d_out, int out_size, void* d_ws, size_t ws_size,
                              hipStream_t stream) {
    // setup_inputs order: x, Wk, Wq, Wv
    const float* x  = (const float*)d_in[0];
    const float* Wk = (const float*)d_in[1];
    const float* Wq = (const float*)d_in[2];
    const float* Wv = (const float*)d_in[3];
    float* ws  = (float*)d_ws;   // q | k | v, each kM*kH fp32 (24 MiB total)
    float* out = (float*)d_out;

    dim3 g1(6, 128);
    hipLaunchKernelGGL(qkv_gemm, g1, dim3(256), 0, stream, x, Wk, Wq, Wv, ws);
    hipLaunchKernelGGL(attn_fp32, dim3(512), dim3(256), 0, stream, ws, out);
}

// Round 2
// 435.618 us; speedup vs baseline: 2.0032x; 2.0032x over previous
//
#include <hip/hip_runtime.h>

// Problem constants: B=8, T=2048, C=1024, H=128
constexpr int kB = 8;
constexpr int kT = 2048;
constexpr int kC = 1024;
constexpr int kH = 128;
constexpr int kM = kB * kT;        // 16384 rows
constexpr int kMH = kM * kH;       // 2,097,152 elements per [M][H] array

typedef __attribute__((ext_vector_type(8))) short bf16x8;   // MFMA A/B frag
typedef __attribute__((ext_vector_type(4))) float f32x4;    // MFMA C/D frag
typedef __attribute__((ext_vector_type(8))) unsigned short u16x8;

__device__ inline unsigned short f2bf(float f) {  // RNE fp32 -> bf16
    union { float f; unsigned int u; } x; x.f = f;
    unsigned int r = x.u + 0x7fff + ((x.u >> 16) & 1);
    return (unsigned short)(r >> 16);
}
__device__ inline float bf2f(unsigned short h) {
    union { float f; unsigned int u; } x; x.u = ((unsigned int)h) << 16;
    return x.f;
}

// ---------------------------------------------------------------------------
// Kernel 1: fused QKV projection (fp32 vector GEMM core, unchanged).
// New epilogue: q -> (32*q) split hi/lo bf16; k -> split hi/lo bf16;
// v -> transposed bf16 vT [B][H][T] so attention staging is a pure copy.
// ws layout (ushort): qhi | qlo | khi | klo | vT   (5 * kMH elements, 20 MB)
// ---------------------------------------------------------------------------
__global__ __launch_bounds__(256) void qkv_gemm(
    const float* __restrict__ x,
    const float* __restrict__ Wk,
    const float* __restrict__ Wq,
    const float* __restrict__ Wv,
    unsigned short* __restrict__ ws)
{
    __shared__ __align__(16) float As[32][132];
    __shared__ __align__(16) float Bs[32][68];

    const int nt  = blockIdx.x & 1;   // col tile (0..1)
    const int mat = blockIdx.x >> 1;  // 0=q, 1=k, 2=v
    const int mt  = blockIdx.y;       // row tile (0..127)

    const float* W = (mat == 0) ? Wq : (mat == 1) ? Wk : Wv;

    const int m0 = mt * 128;
    const int n0 = nt * 64;
    const int tid = threadIdx.x;
    const int tx = tid & 15;
    const int ty = tid >> 4;

    const int alr = tid >> 1;
    const int alk = (tid & 1) * 16;
    const int bkk = tid >> 3;
    const int bc0 = (tid & 7) * 8;

    float acc[8][4];
#pragma unroll
    for (int i = 0; i < 8; ++i)
#pragma unroll
        for (int j = 0; j < 4; ++j) acc[i][j] = 0.0f;

    for (int kt = 0; kt < kC; kt += 32) {
        __syncthreads();
#pragma unroll
        for (int u = 0; u < 4; ++u) {
            const float4 av =
                *(const float4*)(x + (size_t)(m0 + alr) * kC + kt + alk + u * 4);
            As[alk + u * 4 + 0][alr] = av.x;
            As[alk + u * 4 + 1][alr] = av.y;
            As[alk + u * 4 + 2][alr] = av.z;
            As[alk + u * 4 + 3][alr] = av.w;
        }
#pragma unroll
        for (int u = 0; u < 2; ++u) {
            const float4 bv =
                *(const float4*)(W + (size_t)(kt + bkk) * kH + n0 + bc0 + u * 4);
            *(float4*)&Bs[bkk][bc0 + u * 4] = bv;
        }
        __syncthreads();
#pragma unroll
        for (int kk = 0; kk < 32; ++kk) {
            const float4 a0 = *(const float4*)&As[kk][ty * 8];
            const float4 a1 = *(const float4*)&As[kk][ty * 8 + 4];
            const float4 b0 = *(const float4*)&Bs[kk][tx * 4];
            const float a[8] = {a0.x, a0.y, a0.z, a0.w, a1.x, a1.y, a1.z, a1.w};
            const float bb[4] = {b0.x, b0.y, b0.z, b0.w};
#pragma unroll
            for (int i = 0; i < 8; ++i)
#pragma unroll
                for (int j = 0; j < 4; ++j)
                    acc[i][j] = fmaf(a[i], bb[j], acc[i][j]);
        }
    }

    if (mat <= 1) {
        // q (scaled by sqrt(C)=32) or k: split hi/lo bf16, row-major [M][H]
        unsigned short* hip_ = ws + (size_t)(mat * 2) * kMH;
        unsigned short* lop  = ws + (size_t)(mat * 2 + 1) * kMH;
        const float sc = (mat == 0) ? 32.0f : 1.0f;
#pragma unroll
        for (int i = 0; i < 8; ++i) {
            ushort4 h4, l4;
            unsigned short* hv = (unsigned short*)&h4;
            unsigned short* lv = (unsigned short*)&l4;
#pragma unroll
            for (int c = 0; c < 4; ++c) {
                const float f = acc[i][c] * sc;
                const unsigned short hb = f2bf(f);
                hv[c] = hb;
                lv[c] = f2bf(f - bf2f(hb));
            }
            const size_t off = (size_t)(m0 + ty * 8 + i) * kH + n0 + tx * 4;
            *(ushort4*)(hip_ + off) = h4;
            *(ushort4*)(lop + off) = l4;
        }
    } else {
        // v: transposed bf16, vT[b][h][t]
        unsigned short* vtp = ws + (size_t)4 * kMH;
        const int bb = m0 >> 11;               // 128-row tiles never cross batch
        const int t0 = (m0 & (kT - 1)) + ty * 8;
#pragma unroll
        for (int c = 0; c < 4; ++c) {
            const int h = n0 + tx * 4 + c;
            u16x8 pk;
#pragma unroll
            for (int i = 0; i < 8; ++i) pk[i] = f2bf(acc[i][c]);
            *(u16x8*)(vtp + ((size_t)(bb * kH + h)) * kT + t0) = pk;
        }
    }
}

// ---------------------------------------------------------------------------
// Kernel 2: flash attention via MFMA 16x16x32 bf16.
// Block = 128 threads (2 waves). Q tile 32 rows (16/wave), K/V tile 64.
// QK^T: split-bf16 (QhiKhi + QloKhi + QhiKlo) -> fp32-grade logits.
// PV: plain bf16 P and V. P round-trips through per-wave LDS (A-layout).
// Register-prefetch pipeline for global->LDS staging.
// LDS rows padded (+8 bf16) to break power-of-2 bank strides.
// ---------------------------------------------------------------------------
__global__ __launch_bounds__(128) void attn_mfma(
    const unsigned short* __restrict__ ws, float* __restrict__ out)
{
    __shared__ __align__(16) unsigned short KhiS[64][136];
    __shared__ __align__(16) unsigned short KloS[64][136];
    __shared__ __align__(16) unsigned short VtS[128][72];
    __shared__ __align__(16) unsigned short PsS[2][16][72];

    const int tid = threadIdx.x;
    const int w = tid >> 6;        // wave id (0/1)
    const int lane = tid & 63;
    const int li = lane & 15;      // m/n fragment index
    const int quad = lane >> 4;    // k-group / row-group

    const int idx = blockIdx.x;    // 512 blocks
    const int b = idx >> 6;
    const int ii = idx & 63;
    // causal balance: pair heavy qt with light qt
    const int qt = (ii & 1) ? (63 - (ii >> 1)) : (ii >> 1);
    const int i0 = qt * 32;
    const int nj = (qt >> 1) + 1;  // number of 64-wide K tiles

    const unsigned short* qhi = ws;
    const unsigned short* qlo = ws + (size_t)kMH;
    const unsigned short* khi = ws + (size_t)2 * kMH;
    const unsigned short* klo = ws + (size_t)3 * kMH;
    const unsigned short* vt  = ws + (size_t)4 * kMH;   // [B][H][T]

    // --- Q fragments (A-layout: A[m=li][k=quad*8+j]), held in registers ---
    bf16x8 qh[4], ql[4];
    {
        const size_t qoff = ((size_t)(b * kT + i0 + w * 16 + li)) * kH;
#pragma unroll
        for (int kc = 0; kc < 4; ++kc) {
            qh[kc] = *(const bf16x8*)(qhi + qoff + kc * 32 + quad * 8);
            ql[kc] = *(const bf16x8*)(qlo + qoff + kc * 32 + quad * 8);
        }
    }

    f32x4 o[8];
#pragma unroll
    for (int ht = 0; ht < 8; ++ht) o[ht] = (f32x4){0.0f, 0.0f, 0.0f, 0.0f};
    float m_i[4] = {-3.0e38f, -3.0e38f, -3.0e38f, -3.0e38f};
    float l_i[4] = {0.0f, 0.0f, 0.0f, 0.0f};

    const size_t kbase0 = (size_t)(b * kT) * kH;   // khi/klo tile base (flat)
    const size_t vbase0 = (size_t)(b * kH) * kT;   // vT base

    // --- prefetch tile 0 into registers ---
    float4 kh_pf[8], kl_pf[8], v_pf[8];
#pragma unroll
    for (int u = 0; u < 8; ++u) {
        const int f = u * 128 + tid;
        kh_pf[u] = *(const float4*)(khi + kbase0 + (size_t)f * 8);
        kl_pf[u] = *(const float4*)(klo + kbase0 + (size_t)f * 8);
        v_pf[u]  = *(const float4*)(vt + vbase0 + (size_t)(f >> 3) * kT + (f & 7) * 8);
    }

    for (int jt = 0; jt < nj; ++jt) {
        if (jt) __syncthreads();   // all waves done reading previous tile
        // --- commit prefetched tile to LDS ---
#pragma unroll
        for (int u = 0; u < 8; ++u) {
            const int f = u * 128 + tid;
            *(float4*)&KhiS[f >> 4][(f & 15) * 8] = kh_pf[u];
            *(float4*)&KloS[f >> 4][(f & 15) * 8] = kl_pf[u];
            *(float4*)&VtS[f >> 3][(f & 7) * 8]   = v_pf[u];
        }
        __syncthreads();
        // --- issue next tile's global loads (overlap with compute) ---
        if (jt + 1 < nj) {
            const size_t kb = kbase0 + (size_t)(jt + 1) * 64 * kH;
            const size_t vb = vbase0 + (size_t)(jt + 1) * 64;
#pragma unroll
            for (int u = 0; u < 8; ++u) {
                const int f = u * 128 + tid;
                kh_pf[u] = *(const float4*)(khi + kb + (size_t)f * 8);
                kl_pf[u] = *(const float4*)(klo + kb + (size_t)f * 8);
                v_pf[u]  = *(const float4*)(vt + vb + (size_t)(f >> 3) * kT + (f & 7) * 8);
            }
        }

        // --- S = Q K^T via split-bf16 MFMA (4 ntiles x 4 kchunks x 3) ---
        f32x4 s[4];
#pragma unroll
        for (int nt = 0; nt < 4; ++nt) s[nt] = (f32x4){0.0f, 0.0f, 0.0f, 0.0f};
#pragma unroll
        for (int nt = 0; nt < 4; ++nt) {
#pragma unroll
            for (int kc = 0; kc < 4; ++kc) {
                const bf16x8 kh = *(const bf16x8*)&KhiS[nt * 16 + li][kc * 32 + quad * 8];
                const bf16x8 kl = *(const bf16x8*)&KloS[nt * 16 + li][kc * 32 + quad * 8];
                s[nt] = __builtin_amdgcn_mfma_f32_16x16x32_bf16(qh[kc], kh, s[nt], 0, 0, 0);
                s[nt] = __builtin_amdgcn_mfma_f32_16x16x32_bf16(ql[kc], kh, s[nt], 0, 0, 0);
                s[nt] = __builtin_amdgcn_mfma_f32_16x16x32_bf16(qh[kc], kl, s[nt], 0, 0, 0);
            }
        }

        // --- causal mask (last tile only). C-layout: row=quad*4+reg, col=li ---
        if (jt == nj - 1) {
            const int grow0 = i0 + w * 16 + quad * 4;
            const int gcol0 = jt * 64 + li;
#pragma unroll
            for (int nt = 0; nt < 4; ++nt)
#pragma unroll
                for (int reg = 0; reg < 4; ++reg)
                    if (gcol0 + nt * 16 > grow0 + reg) s[nt][reg] = -3.0e38f;
        }

        // --- online softmax (row reductions over lane bits 0..3) ---
        float alpha[4];
#pragma unroll
        for (int reg = 0; reg < 4; ++reg) {
            float mr = fmaxf(fmaxf(s[0][reg], s[1][reg]), fmaxf(s[2][reg], s[3][reg]));
            mr = fmaxf(mr, __shfl_xor(mr, 1));
            mr = fmaxf(mr, __shfl_xor(mr, 2));
            mr = fmaxf(mr, __shfl_xor(mr, 4));
            mr = fmaxf(mr, __shfl_xor(mr, 8));
            const float mn = fmaxf(m_i[reg], mr);
            alpha[reg] = __expf(m_i[reg] - mn);
            m_i[reg] = mn;
            float rs = 0.0f;
#pragma unroll
            for (int nt = 0; nt < 4; ++nt) {
                const float p = __expf(s[nt][reg] - mn);
                s[nt][reg] = p;
                rs += p;
            }
            rs += __shfl_xor(rs, 1);
            rs += __shfl_xor(rs, 2);
            rs += __shfl_xor(rs, 4);
            rs += __shfl_xor(rs, 8);
            l_i[reg] = l_i[reg] * alpha[reg] + rs;
        }
        const f32x4 av = {alpha[0], alpha[1], alpha[2], alpha[3]};
#pragma unroll
        for (int ht = 0; ht < 8; ++ht) o[ht] *= av;

        // --- publish P (C-layout -> [i][j] bf16 in per-wave LDS) ---
#pragma unroll
        for (int nt = 0; nt < 4; ++nt)
#pragma unroll
            for (int reg = 0; reg < 4; ++reg)
                PsS[w][quad * 4 + reg][nt * 16 + li] = f2bf(s[nt][reg]);

        // --- O += P V (same-wave LDS round-trip; ds ops in-order per wave) ---
        const bf16x8 p0 = *(const bf16x8*)&PsS[w][li][quad * 8];
        const bf16x8 p1 = *(const bf16x8*)&PsS[w][li][32 + quad * 8];
#pragma unroll
        for (int ht = 0; ht < 8; ++ht) {
            const bf16x8 v0 = *(const bf16x8*)&VtS[ht * 16 + li][quad * 8];
            const bf16x8 v1 = *(const bf16x8*)&VtS[ht * 16 + li][32 + quad * 8];
            o[ht] = __builtin_amdgcn_mfma_f32_16x16x32_bf16(p0, v0, o[ht], 0, 0, 0);
            o[ht] = __builtin_amdgcn_mfma_f32_16x16x32_bf16(p1, v1, o[ht], 0, 0, 0);
        }
    }

    // --- epilogue: O / l ---
    float inv[4];
#pragma unroll
    for (int reg = 0; reg < 4; ++reg) inv[reg] = 1.0f / l_i[reg];
#pragma unroll
    for (int ht = 0; ht < 8; ++ht) {
#pragma unroll
        for (int reg = 0; reg < 4; ++reg) {
            out[(size_t)(b * kT + i0 + w * 16 + quad * 4 + reg) * kH + ht * 16 + li] =
                o[ht][reg] * inv[reg];
        }
    }
}

// ---------------------------------------------------------------------------
extern "C" void kernel_launch(void* const* d_in, const int* in_sizes, int n_in,
                              void* d_out, int out_size, void* d_ws, size_t ws_size,
                              hipStream_t stream) {
    // setup_inputs order: x, Wk, Wq, Wv
    const float* x  = (const float*)d_in[0];
    const float* Wk = (const float*)d_in[1];
    const float* Wq = (const float*)d_in[2];
    const float* Wv = (const float*)d_in[3];
    unsigned short* ws = (unsigned short*)d_ws;  // qhi|qlo|khi|klo|vT (20 MB)
    float* out = (float*)d_out;

    hipLaunchKernelGGL(qkv_gemm, dim3(6, 128), dim3(256), 0, stream,
                       x, Wk, Wq, Wv, ws);
    hipLaunchKernelGGL(attn_mfma, dim3(512), dim3(128), 0, stream,
                       (const unsigned short*)ws, out);
}

// Round 3
// 235.073 us; speedup vs baseline: 3.7121x; 1.8531x over previous
//
#include <hip/hip_runtime.h>

// Problem constants: B=8, T=2048, C=1024, H=128
constexpr int kB = 8;
constexpr int kT = 2048;
constexpr int kC = 1024;
constexpr int kH = 128;
constexpr int kM = kB * kT;                 // 16384 rows
constexpr size_t kMH = (size_t)kM * kH;     // 2,097,152
constexpr size_t kWH = (size_t)kC * kH;     // 131,072

typedef __attribute__((ext_vector_type(8))) short bf16x8;   // MFMA A/B frag
typedef __attribute__((ext_vector_type(4))) float f32x4;    // MFMA C/D frag

// ws layout (ushort elements):
//   [0)       qhi   (kMH)     q*32, hi16-truncated bf16, [M][H]
//   [1*kMH)   qlo                     residual bf16
//   [2*kMH)   khi
//   [3*kMH)   klo
//   [4*kMH)   vT    [B][H][T] bf16 (RNE)
//   [5*kMH)   wqT_hi/wqT_lo/wkT_hi/wkT_lo/wvT_hi/wvT_lo, each kWH, [H][C]
// total ~22.6 MB

__device__ inline unsigned short f2bf_rne(float f) {
    union { float f; unsigned int u; } x; x.f = f;
    unsigned int r = x.u + 0x7fff + ((x.u >> 16) & 1);
    return (unsigned short)(r >> 16);
}
// pack hi16(a) into low half, hi16(b) into high half
__device__ inline unsigned int pack_hi2(float a, float b) {
    return __builtin_amdgcn_perm(__float_as_uint(b), __float_as_uint(a),
                                 0x07060302u);
}
__device__ inline float hi_part(float v) {
    return __uint_as_float(__float_as_uint(v) & 0xffff0000u);
}
// async global->LDS, 16 bytes per lane (DMA; LDS dest = uniform base + lane*16)
__device__ inline void load_lds16(const unsigned short* g, unsigned short* l) {
    __builtin_amdgcn_global_load_lds(
        (const __attribute__((address_space(1))) unsigned int*)g,
        (__attribute__((address_space(3))) unsigned int*)l, 16, 0, 0);
}

// ---------------------------------------------------------------------------
// Kernel 0: split + transpose weights -> WT_hi/WT_lo [H][C] bf16.
// grid (128, 3) = (h, mat), 256 threads: thread t handles k = 4t..4t+3.
// ---------------------------------------------------------------------------
__global__ __launch_bounds__(256) void prep_w(
    const float* __restrict__ Wk, const float* __restrict__ Wq,
    const float* __restrict__ Wv, unsigned short* __restrict__ ws)
{
    const int h = blockIdx.x;
    const int mat = blockIdx.y;
    const float* W = (mat == 0) ? Wq : (mat == 1) ? Wk : Wv;
    unsigned short* hi = ws + 5 * kMH + (size_t)(mat * 2) * kWH;
    unsigned short* lo = hi + kWH;

    const int k0 = threadIdx.x * 4;
    float f[4], l[4];
#pragma unroll
    for (int j = 0; j < 4; ++j) {
        f[j] = W[(size_t)(k0 + j) * kH + h];
        l[j] = f[j] - hi_part(f[j]);
    }
    const uint2 hv = make_uint2(pack_hi2(f[0], f[1]), pack_hi2(f[2], f[3]));
    const uint2 lv = make_uint2(pack_hi2(l[0], l[1]), pack_hi2(l[2], l[3]));
    *(uint2*)&hi[(size_t)h * kC + k0] = hv;
    *(uint2*)&lo[(size_t)h * kC + k0] = lv;
}

// ---------------------------------------------------------------------------
// Kernel 1: QKV projection via split-bf16 MFMA.
// grid (3, 128) = (mat, row-tile). 256 threads = 4 waves in a 2x2 grid;
// each wave computes 64x64 of the 128x128 output tile. K-step 64.
// acc += Ahi*Bhi + Alo*Bhi + Ahi*Blo  (fp32-grade product).
// Epilogue: mat 0/1 -> hi/lo split [M][H]; mat 2 -> RNE bf16 vT [B][H][T].
// ---------------------------------------------------------------------------
__global__ __launch_bounds__(256, 2) void qkv_mfma(
    const float* __restrict__ x, unsigned short* __restrict__ ws)
{
    __shared__ __align__(16) unsigned short Ahi[128][72];
    __shared__ __align__(16) unsigned short Alo[128][72];
    __shared__ __align__(16) unsigned short Bhi[128][72];
    __shared__ __align__(16) unsigned short Blo[128][72];

    const int mat = blockIdx.x;
    const int m0 = blockIdx.y * 128;
    const unsigned short* wThi = ws + 5 * kMH + (size_t)(mat * 2) * kWH;
    const unsigned short* wTlo = wThi + kWH;

    const int tid = threadIdx.x;
    const int w = tid >> 6;
    const int lane = tid & 63;
    const int li = lane & 15;
    const int quad = lane >> 4;
    const int wm = w >> 1;     // wave m-half (0/1)
    const int wn = w & 1;      // wave n-half (0/1)

    f32x4 acc[4][4];
#pragma unroll
    for (int i = 0; i < 4; ++i)
#pragma unroll
        for (int j = 0; j < 4; ++j) acc[i][j] = (f32x4){0.f, 0.f, 0.f, 0.f};

    for (int kt = 0; kt < kC; kt += 64) {
        if (kt) __syncthreads();
        // ---- stage x tile [128][64] fp32 -> hi/lo bf16 LDS ----
#pragma unroll
        for (int u = 0; u < 8; ++u) {
            const int f = u * 256 + tid;
            const int row = f >> 4;
            const int c = (f & 15) * 4;
            const float4 xv = *(const float4*)(x + (size_t)(m0 + row) * kC + kt + c);
            const unsigned int h01 = pack_hi2(xv.x, xv.y);
            const unsigned int h23 = pack_hi2(xv.z, xv.w);
            const float l0 = xv.x - hi_part(xv.x);
            const float l1 = xv.y - hi_part(xv.y);
            const float l2 = xv.z - hi_part(xv.z);
            const float l3 = xv.w - hi_part(xv.w);
            *(uint2*)&Ahi[row][c] = make_uint2(h01, h23);
            *(uint2*)&Alo[row][c] = make_uint2(pack_hi2(l0, l1), pack_hi2(l2, l3));
        }
        // ---- stage WT tiles [128][64] bf16 ----
#pragma unroll
        for (int u = 0; u < 4; ++u) {
            const int f = u * 256 + tid;
            const int row = f >> 3;
            const int g = (f & 7) * 8;
            *(uint4*)&Bhi[row][g] = *(const uint4*)(wThi + (size_t)row * kC + kt + g);
            *(uint4*)&Blo[row][g] = *(const uint4*)(wTlo + (size_t)row * kC + kt + g);
        }
        __syncthreads();

        // ---- MFMA: 2 k-chunks x 4 n x 4 m x 3 splits ----
#pragma unroll
        for (int kc = 0; kc < 2; ++kc) {
            bf16x8 ah[4], al[4];
#pragma unroll
            for (int mt = 0; mt < 4; ++mt) {
                ah[mt] = *(const bf16x8*)&Ahi[wm * 64 + mt * 16 + li][kc * 32 + quad * 8];
                al[mt] = *(const bf16x8*)&Alo[wm * 64 + mt * 16 + li][kc * 32 + quad * 8];
            }
#pragma unroll
            for (int nt = 0; nt < 4; ++nt) {
                const bf16x8 bh = *(const bf16x8*)&Bhi[wn * 64 + nt * 16 + li][kc * 32 + quad * 8];
                const bf16x8 bl = *(const bf16x8*)&Blo[wn * 64 + nt * 16 + li][kc * 32 + quad * 8];
#pragma unroll
                for (int mt = 0; mt < 4; ++mt) {
                    acc[mt][nt] = __builtin_amdgcn_mfma_f32_16x16x32_bf16(ah[mt], bh, acc[mt][nt], 0, 0, 0);
                    acc[mt][nt] = __builtin_amdgcn_mfma_f32_16x16x32_bf16(al[mt], bh, acc[mt][nt], 0, 0, 0);
                    acc[mt][nt] = __builtin_amdgcn_mfma_f32_16x16x32_bf16(ah[mt], bl, acc[mt][nt], 0, 0, 0);
                }
            }
        }
    }

    // ---- epilogue ----
    const int gm0 = m0 + wm * 64;
    const int gn0 = wn * 64;
    if (mat <= 1) {
        unsigned short* hip_ = ws + (size_t)(mat * 2) * kMH;
        unsigned short* lop  = hip_ + kMH;
        const float sc = (mat == 0) ? 32.0f : 1.0f;
#pragma unroll
        for (int mt = 0; mt < 4; ++mt)
#pragma unroll
            for (int nt = 0; nt < 4; ++nt) {
                const int col = gn0 + nt * 16 + li;
#pragma unroll
                for (int reg = 0; reg < 4; ++reg) {
                    const int row = gm0 + mt * 16 + quad * 4 + reg;
                    const float v = acc[mt][nt][reg] * sc;
                    const float hf = hi_part(v);
                    hip_[(size_t)row * kH + col] = (unsigned short)(__float_as_uint(v) >> 16);
                    lop[(size_t)row * kH + col] =
                        (unsigned short)(__float_as_uint(v - hf) >> 16);
                }
            }
    } else {
        unsigned short* vt = ws + 4 * kMH;
        const int bb = m0 >> 11;
        const int t00 = gm0 & (kT - 1);
#pragma unroll
        for (int mt = 0; mt < 4; ++mt)
#pragma unroll
            for (int nt = 0; nt < 4; ++nt) {
                const int h = gn0 + nt * 16 + li;
                ushort4 pk;
                pk.x = f2bf_rne(acc[mt][nt][0]);
                pk.y = f2bf_rne(acc[mt][nt][1]);
                pk.z = f2bf_rne(acc[mt][nt][2]);
                pk.w = f2bf_rne(acc[mt][nt][3]);
                const int t0 = t00 + mt * 16 + quad * 4;
                *(ushort4*)&vt[((size_t)(bb * kH + h)) * kT + t0] = pk;
            }
    }
}

// ---------------------------------------------------------------------------
// Kernel 2: flash attention, MFMA 16x16x32 bf16, DMA-staged, XOR-swizzled LDS.
// 128 threads (2 waves), Q=32 rows (16/wave), K/V tile 64, grid 512.
// LDS flat (DMA needs contiguity); bank conflicts broken by sourcing granule
// p of row r from global granule p^(r&15) (K) / p^(h&7) (V); frag reads apply
// the same XOR. Single-buffered (m97 pattern), 53.8 KB -> 3 blocks/CU.
// ---------------------------------------------------------------------------
__global__ __launch_bounds__(128) void attn_mfma(
    const unsigned short* __restrict__ ws, float* __restrict__ out)
{
    __shared__ __align__(16) unsigned short KhiS[64 * 128];
    __shared__ __align__(16) unsigned short KloS[64 * 128];
    __shared__ __align__(16) unsigned short VtS[128 * 64];
    __shared__ __align__(16) unsigned short Ps[2][16][72];

    const int tid = threadIdx.x;
    const int w = tid >> 6;
    const int lane = tid & 63;
    const int li = lane & 15;
    const int quad = lane >> 4;

    const int idx = blockIdx.x;
    const int b = idx >> 6;
    const int ii = idx & 63;
    const int qt = (ii & 1) ? (63 - (ii >> 1)) : (ii >> 1);   // balance pairing
    const int i0 = qt * 32;
    const int nj = (qt >> 1) + 1;

    const unsigned short* qhi = ws;
    const unsigned short* qlo = ws + kMH;
    const unsigned short* khi = ws + 2 * kMH;
    const unsigned short* klo = ws + 3 * kMH;
    const unsigned short* vt  = ws + 4 * kMH;

    // Q fragments in registers (A-layout)
    bf16x8 qh[4], ql[4];
    {
        const size_t qoff = ((size_t)(b * kT + i0 + w * 16 + li)) * kH;
#pragma unroll
        for (int kc = 0; kc < 4; ++kc) {
            qh[kc] = *(const bf16x8*)(qhi + qoff + kc * 32 + quad * 8);
            ql[kc] = *(const bf16x8*)(qlo + qoff + kc * 32 + quad * 8);
        }
    }

    f32x4 o[8];
#pragma unroll
    for (int ht = 0; ht < 8; ++ht) o[ht] = (f32x4){0.f, 0.f, 0.f, 0.f};
    float m_i[4] = {-3.0e38f, -3.0e38f, -3.0e38f, -3.0e38f};
    float l_i[4] = {0.f, 0.f, 0.f, 0.f};

    for (int jt = 0; jt < nj; ++jt) {
        if (jt) __syncthreads();
        // ---- DMA stage K/V tile (swizzled source) ----
        {
            const size_t kgb = ((size_t)(b * kT + jt * 64)) * kH;
#pragma unroll
            for (int u = 0; u < 8; ++u) {
                const int f = u * 128 + tid;
                const int r = f >> 4, p = f & 15;
                const int g = p ^ (r & 15);
                load_lds16(khi + kgb + r * 128 + g * 8, &KhiS[f * 8]);
                load_lds16(klo + kgb + r * 128 + g * 8, &KloS[f * 8]);
            }
#pragma unroll
            for (int u = 0; u < 8; ++u) {
                const int f = u * 128 + tid;
                const int h = f >> 3, p = f & 7;
                const int g = p ^ (h & 7);
                load_lds16(vt + (size_t)(b * kH + h) * kT + jt * 64 + g * 8,
                           &VtS[f * 8]);
            }
        }
        __syncthreads();

        // ---- S = Q K^T (split-bf16) ----
        f32x4 s[4];
#pragma unroll
        for (int nt = 0; nt < 4; ++nt) s[nt] = (f32x4){0.f, 0.f, 0.f, 0.f};
#pragma unroll
        for (int nt = 0; nt < 4; ++nt) {
            const int r = nt * 16 + li;
#pragma unroll
            for (int kc = 0; kc < 4; ++kc) {
                const int pos = (kc * 4 + quad) ^ (r & 15);
                const bf16x8 kh = *(const bf16x8*)&KhiS[r * 128 + pos * 8];
                const bf16x8 kl = *(const bf16x8*)&KloS[r * 128 + pos * 8];
                s[nt] = __builtin_amdgcn_mfma_f32_16x16x32_bf16(qh[kc], kh, s[nt], 0, 0, 0);
                s[nt] = __builtin_amdgcn_mfma_f32_16x16x32_bf16(ql[kc], kh, s[nt], 0, 0, 0);
                s[nt] = __builtin_amdgcn_mfma_f32_16x16x32_bf16(qh[kc], kl, s[nt], 0, 0, 0);
            }
        }

        // ---- causal mask on diagonal tile ----
        if (jt == nj - 1) {
            const int grow0 = i0 + w * 16 + quad * 4;
            const int gcol0 = jt * 64 + li;
#pragma unroll
            for (int nt = 0; nt < 4; ++nt)
#pragma unroll
                for (int reg = 0; reg < 4; ++reg)
                    if (gcol0 + nt * 16 > grow0 + reg) s[nt][reg] = -3.0e38f;
        }

        // ---- online softmax ----
        float alpha[4];
#pragma unroll
        for (int reg = 0; reg < 4; ++reg) {
            float mr = fmaxf(fmaxf(s[0][reg], s[1][reg]), fmaxf(s[2][reg], s[3][reg]));
            mr = fmaxf(mr, __shfl_xor(mr, 1));
            mr = fmaxf(mr, __shfl_xor(mr, 2));
            mr = fmaxf(mr, __shfl_xor(mr, 4));
            mr = fmaxf(mr, __shfl_xor(mr, 8));
            const float mn = fmaxf(m_i[reg], mr);
            alpha[reg] = __expf(m_i[reg] - mn);
            m_i[reg] = mn;
            float rs = 0.f;
#pragma unroll
            for (int nt = 0; nt < 4; ++nt) {
                const float p = __expf(s[nt][reg] - mn);
                s[nt][reg] = p;
                rs += p;
            }
            rs += __shfl_xor(rs, 1);
            rs += __shfl_xor(rs, 2);
            rs += __shfl_xor(rs, 4);
            rs += __shfl_xor(rs, 8);
            l_i[reg] = l_i[reg] * alpha[reg] + rs;
        }
        const f32x4 av = {alpha[0], alpha[1], alpha[2], alpha[3]};
#pragma unroll
        for (int ht = 0; ht < 8; ++ht) o[ht] *= av;

        // ---- publish P (per-wave LDS, padded) ----
#pragma unroll
        for (int nt = 0; nt < 4; ++nt)
#pragma unroll
            for (int reg = 0; reg < 4; ++reg)
                Ps[w][quad * 4 + reg][nt * 16 + li] = f2bf_rne(s[nt][reg]);

        // ---- O += P V (same-wave LDS round-trip; V reads swizzled) ----
        const bf16x8 p0 = *(const bf16x8*)&Ps[w][li][quad * 8];
        const bf16x8 p1 = *(const bf16x8*)&Ps[w][li][32 + quad * 8];
#pragma unroll
        for (int ht = 0; ht < 8; ++ht) {
            const int hrow = ht * 16 + li;
            const int pa = (quad) ^ (hrow & 7);
            const int pb = (4 + quad) ^ (hrow & 7);
            const bf16x8 v0 = *(const bf16x8*)&VtS[hrow * 64 + pa * 8];
            const bf16x8 v1 = *(const bf16x8*)&VtS[hrow * 64 + pb * 8];
            o[ht] = __builtin_amdgcn_mfma_f32_16x16x32_bf16(p0, v0, o[ht], 0, 0, 0);
            o[ht] = __builtin_amdgcn_mfma_f32_16x16x32_bf16(p1, v1, o[ht], 0, 0, 0);
        }
    }

    // ---- epilogue: O / l ----
    float inv[4];
#pragma unroll
    for (int reg = 0; reg < 4; ++reg) inv[reg] = 1.0f / l_i[reg];
#pragma unroll
    for (int ht = 0; ht < 8; ++ht)
#pragma unroll
        for (int reg = 0; reg < 4; ++reg)
            out[(size_t)(b * kT + i0 + w * 16 + quad * 4 + reg) * kH + ht * 16 + li] =
                o[ht][reg] * inv[reg];
}

// ---------------------------------------------------------------------------
extern "C" void kernel_launch(void* const* d_in, const int* in_sizes, int n_in,
                              void* d_out, int out_size, void* d_ws, size_t ws_size,
                              hipStream_t stream) {
    // setup_inputs order: x, Wk, Wq, Wv
    const float* x  = (const float*)d_in[0];
    const float* Wk = (const float*)d_in[1];
    const float* Wq = (const float*)d_in[2];
    const float* Wv = (const float*)d_in[3];
    unsigned short* ws = (unsigned short*)d_ws;
    float* out = (float*)d_out;

    hipLaunchKernelGGL(prep_w, dim3(128, 3), dim3(256), 0, stream, Wk, Wq, Wv, ws);
    hipLaunchKernelGGL(qkv_mfma, dim3(3, 128), dim3(256), 0, stream, x, ws);
    hipLaunchKernelGGL(attn_mfma, dim3(512), dim3(128), 0, stream,
                       (const unsigned short*)ws, out);
}

// Round 4
// 216.626 us; speedup vs baseline: 4.0282x; 1.0852x over previous
//
#include <hip/hip_runtime.h>

// Problem constants: B=8, T=2048, C=1024, H=128
constexpr int kB = 8;
constexpr int kT = 2048;
constexpr int kC = 1024;
constexpr int kH = 128;
constexpr int kM = kB * kT;                 // 16384 rows
constexpr size_t kMH = (size_t)kM * kH;     // 2,097,152
constexpr size_t kWH = (size_t)kC * kH;     // 131,072

typedef __attribute__((ext_vector_type(8))) short bf16x8;   // MFMA A/B frag
typedef __attribute__((ext_vector_type(4))) float f32x4;    // MFMA C/D frag

// ws layout (ushort): qhi | qlo | khi | klo | vT[B][H][T] | 6x WT (hi/lo per mat)

__device__ inline unsigned short f2bf_rne(float f) {
    union { float f; unsigned int u; } x; x.f = f;
    unsigned int r = x.u + 0x7fff + ((x.u >> 16) & 1);
    return (unsigned short)(r >> 16);
}
__device__ inline float bf2f(unsigned short h) {
    union { float f; unsigned int u; } x; x.u = ((unsigned int)h) << 16;
    return x.f;
}
__device__ inline unsigned int pack_hi2(float a, float b) {  // trunc-hi16 pack
    return __builtin_amdgcn_perm(__float_as_uint(b), __float_as_uint(a),
                                 0x07060302u);
}
__device__ inline float hi_part(float v) {
    return __uint_as_float(__float_as_uint(v) & 0xffff0000u);
}
__device__ inline void load_lds16(const unsigned short* g, unsigned short* l) {
    __builtin_amdgcn_global_load_lds(
        (const __attribute__((address_space(1))) unsigned int*)g,
        (__attribute__((address_space(3))) unsigned int*)l, 16, 0, 0);
}
#define RAW_BARRIER()  asm volatile("s_barrier" ::: "memory")
#define WAIT_VM0()     asm volatile("s_waitcnt vmcnt(0)" ::: "memory")

// ---------------------------------------------------------------------------
// Kernel 0: split + transpose weights -> WT_hi (RNE) / WT_lo [H][C] bf16.
// ---------------------------------------------------------------------------
__global__ __launch_bounds__(256) void prep_w(
    const float* __restrict__ Wk, const float* __restrict__ Wq,
    const float* __restrict__ Wv, unsigned short* __restrict__ ws)
{
    const int h = blockIdx.x;
    const int mat = blockIdx.y;
    const float* W = (mat == 0) ? Wq : (mat == 1) ? Wk : Wv;
    unsigned short* hi = ws + 5 * kMH + (size_t)(mat * 2) * kWH;
    unsigned short* lo = hi + kWH;

    const int k0 = threadIdx.x * 4;
    unsigned short hv[4], lv[4];
#pragma unroll
    for (int j = 0; j < 4; ++j) {
        const float f = W[(size_t)(k0 + j) * kH + h];
        hv[j] = f2bf_rne(f);
        lv[j] = f2bf_rne(f - bf2f(hv[j]));
    }
    *(uint2*)&hi[(size_t)h * kC + k0] =
        make_uint2(((unsigned)hv[1] << 16) | hv[0], ((unsigned)hv[3] << 16) | hv[2]);
    *(uint2*)&lo[(size_t)h * kC + k0] =
        make_uint2(((unsigned)lv[1] << 16) | lv[0], ((unsigned)lv[3] << 16) | lv[2]);
}

// ---------------------------------------------------------------------------
// Kernel 1: QKV projection. 512 blocks:
//   idx<256:  heavy q/k block  (mat=idx&1, M=128, split-bf16, 96 MFMA/iter)
//   idx>=256: light v block    (M=64, single RNE bf16 product, 16 MFMA/iter)
// CU c co-hosts heavy c + light c+256 -> balanced, 8 waves/CU.
// B tiles staged via global_load_lds (swizzled); A staged via VALU convert.
// ---------------------------------------------------------------------------
__global__ __launch_bounds__(256, 2) void qkv_mfma(
    const float* __restrict__ x, unsigned short* __restrict__ ws)
{
    __shared__ __align__(16) unsigned short lds[34816];  // 69,632 B
    unsigned short* Ahi = lds;            // heavy: [128][72] / light: [64][72]
    unsigned short* Alo = lds + 9216;
    unsigned short* Bh  = lds + 18432;    // flat [128][64]
    unsigned short* Bl  = lds + 26624;

    const int idx = blockIdx.x;
    const int tid = threadIdx.x;
    const int w = tid >> 6, lane = tid & 63;
    const int li = lane & 15, quad = lane >> 4;

    if (idx < 256) {
        // ----------------- heavy q/k -----------------
        const int mat = idx & 1;
        const int m0 = (idx >> 1) * 128;
        const unsigned short* wThi = ws + 5 * kMH + (size_t)(mat * 2) * kWH;
        const unsigned short* wTlo = wThi + kWH;
        const int wm = w >> 1, wn = w & 1;

        f32x4 acc[4][4];
#pragma unroll
        for (int i = 0; i < 4; ++i)
#pragma unroll
            for (int j = 0; j < 4; ++j) acc[i][j] = (f32x4){0.f, 0.f, 0.f, 0.f};

        for (int kt = 0; kt < kC; kt += 64) {
            if (kt) __syncthreads();
            // A: x [128][64] fp32 -> trunc hi/lo bf16
#pragma unroll
            for (int u = 0; u < 8; ++u) {
                const int f = u * 256 + tid;
                const int row = f >> 4, c4 = (f & 15) * 4;
                const float4 xv =
                    *(const float4*)(x + (size_t)(m0 + row) * kC + kt + c4);
                const float l0 = xv.x - hi_part(xv.x), l1 = xv.y - hi_part(xv.y);
                const float l2 = xv.z - hi_part(xv.z), l3 = xv.w - hi_part(xv.w);
                *(uint2*)&Ahi[row * 72 + c4] =
                    make_uint2(pack_hi2(xv.x, xv.y), pack_hi2(xv.z, xv.w));
                *(uint2*)&Alo[row * 72 + c4] =
                    make_uint2(pack_hi2(l0, l1), pack_hi2(l2, l3));
            }
            // B: DMA [128][64] hi+lo, granule-swizzled
#pragma unroll
            for (int u = 0; u < 4; ++u) {
                const int f = u * 256 + tid;
                const int row = f >> 3, p = f & 7, g = p ^ (row & 7);
                load_lds16(wThi + (size_t)row * kC + kt + g * 8, Bh + f * 8);
                load_lds16(wTlo + (size_t)row * kC + kt + g * 8, Bl + f * 8);
            }
            __syncthreads();

#pragma unroll
            for (int kc = 0; kc < 2; ++kc) {
                bf16x8 ah[4], al[4];
#pragma unroll
                for (int mt = 0; mt < 4; ++mt) {
                    const int ar = (wm * 64 + mt * 16 + li) * 72 + kc * 32 + quad * 8;
                    ah[mt] = *(const bf16x8*)&Ahi[ar];
                    al[mt] = *(const bf16x8*)&Alo[ar];
                }
#pragma unroll
                for (int nt = 0; nt < 4; ++nt) {
                    const int row = wn * 64 + nt * 16 + li;
                    const int pos = (kc * 4 + quad) ^ (li & 7);
                    const bf16x8 bh = *(const bf16x8*)&Bh[row * 64 + pos * 8];
                    const bf16x8 bl = *(const bf16x8*)&Bl[row * 64 + pos * 8];
#pragma unroll
                    for (int mt = 0; mt < 4; ++mt) {
                        acc[mt][nt] = __builtin_amdgcn_mfma_f32_16x16x32_bf16(ah[mt], bh, acc[mt][nt], 0, 0, 0);
                        acc[mt][nt] = __builtin_amdgcn_mfma_f32_16x16x32_bf16(al[mt], bh, acc[mt][nt], 0, 0, 0);
                        acc[mt][nt] = __builtin_amdgcn_mfma_f32_16x16x32_bf16(ah[mt], bl, acc[mt][nt], 0, 0, 0);
                    }
                }
            }
        }
        // epilogue: hi/lo split [M][H] (q scaled by 32)
        unsigned short* hip_ = ws + (size_t)(mat * 2) * kMH;
        unsigned short* lop  = hip_ + kMH;
        const float sc = (mat == 0) ? 32.0f : 1.0f;
#pragma unroll
        for (int mt = 0; mt < 4; ++mt)
#pragma unroll
            for (int nt = 0; nt < 4; ++nt) {
                const int col = wn * 64 + nt * 16 + li;
#pragma unroll
                for (int reg = 0; reg < 4; ++reg) {
                    const int row = m0 + wm * 64 + mt * 16 + quad * 4 + reg;
                    const float v = acc[mt][nt][reg] * sc;
                    hip_[(size_t)row * kH + col] = (unsigned short)(__float_as_uint(v) >> 16);
                    lop[(size_t)row * kH + col] =
                        (unsigned short)(__float_as_uint(v - hi_part(v)) >> 16);
                }
            }
    } else {
        // ----------------- light v -----------------
        const int m0 = (idx - 256) * 64;
        const unsigned short* wThi = ws + 5 * kMH + (size_t)4 * kWH;
        const int rm = w >> 1, rn = w & 1;

        f32x4 acc[2][4];
#pragma unroll
        for (int i = 0; i < 2; ++i)
#pragma unroll
            for (int j = 0; j < 4; ++j) acc[i][j] = (f32x4){0.f, 0.f, 0.f, 0.f};

        for (int kt = 0; kt < kC; kt += 64) {
            if (kt) __syncthreads();
            // A: x [64][64] fp32 -> RNE bf16
#pragma unroll
            for (int u = 0; u < 4; ++u) {
                const int f = u * 256 + tid;
                const int row = f >> 4, c4 = (f & 15) * 4;
                const float4 xv =
                    *(const float4*)(x + (size_t)(m0 + row) * kC + kt + c4);
                unsigned short h0 = f2bf_rne(xv.x), h1 = f2bf_rne(xv.y);
                unsigned short h2 = f2bf_rne(xv.z), h3 = f2bf_rne(xv.w);
                *(uint2*)&Ahi[row * 72 + c4] =
                    make_uint2(((unsigned)h1 << 16) | h0, ((unsigned)h3 << 16) | h2);
            }
#pragma unroll
            for (int u = 0; u < 4; ++u) {
                const int f = u * 256 + tid;
                const int row = f >> 3, p = f & 7, g = p ^ (row & 7);
                load_lds16(wThi + (size_t)row * kC + kt + g * 8, Bh + f * 8);
            }
            __syncthreads();

#pragma unroll
            for (int kc = 0; kc < 2; ++kc) {
                bf16x8 a[2];
#pragma unroll
                for (int mt = 0; mt < 2; ++mt)
                    a[mt] = *(const bf16x8*)&Ahi[(rm * 32 + mt * 16 + li) * 72 + kc * 32 + quad * 8];
#pragma unroll
                for (int nt = 0; nt < 4; ++nt) {
                    const int row = rn * 64 + nt * 16 + li;
                    const int pos = (kc * 4 + quad) ^ (li & 7);
                    const bf16x8 bh = *(const bf16x8*)&Bh[row * 64 + pos * 8];
#pragma unroll
                    for (int mt = 0; mt < 2; ++mt)
                        acc[mt][nt] = __builtin_amdgcn_mfma_f32_16x16x32_bf16(a[mt], bh, acc[mt][nt], 0, 0, 0);
                }
            }
        }
        // epilogue: vT [B][H][T] bf16 RNE
        unsigned short* vt = ws + 4 * kMH;
        const int bb = m0 >> 11;
        const int t00 = m0 & (kT - 1);
#pragma unroll
        for (int mt = 0; mt < 2; ++mt)
#pragma unroll
            for (int nt = 0; nt < 4; ++nt) {
                const int h = rn * 64 + nt * 16 + li;
                ushort4 pk;
                pk.x = f2bf_rne(acc[mt][nt][0]);
                pk.y = f2bf_rne(acc[mt][nt][1]);
                pk.z = f2bf_rne(acc[mt][nt][2]);
                pk.w = f2bf_rne(acc[mt][nt][3]);
                const int t0 = t00 + rm * 32 + mt * 16 + quad * 4;
                *(ushort4*)&vt[((size_t)(bb * kH + h)) * kT + t0] = pk;
            }
    }
}

// ---------------------------------------------------------------------------
// Kernel 2: flash attention. 512 blocks x 4 waves. Wave (r,c): q-rows
// i0+16r.., k-col half c of each 64-wide K tile. Per-c (m,l,O) merged at end
// (flash-decoding). K hi/lo double-buffered via DMA (separate LDS objects);
// V read straight from global into B-frags. Raw s_barrier + manual vmcnt(0)
// keeps next tile's DMA in flight across the barrier.
// Balance: b=idx&7 (batch->XCD), qt=(j<32)?j:95-j so co-resident blocks
// c/c+256 carry qt and 63-qt -> ~33 tiles per SIMD.
// ---------------------------------------------------------------------------
__global__ __launch_bounds__(256, 2) void attn_mfma(
    const unsigned short* __restrict__ ws, float* __restrict__ out)
{
    __shared__ __align__(16) unsigned short Kh0[64 * 128];
    __shared__ __align__(16) unsigned short Kl0[64 * 128];
    __shared__ __align__(16) unsigned short Kh1[64 * 128];
    __shared__ __align__(16) unsigned short Kl1[64 * 128];
    __shared__ __align__(16) unsigned short Ps[4][16][40];
    __shared__ __align__(16) float Ml[2][2][2][16];       // [r][c][m|l][row]
    __shared__ __align__(16) unsigned short Os[2][16][136];

    const int tid = threadIdx.x;
    const int w = tid >> 6, lane = tid & 63;
    const int li = lane & 15, quad = lane >> 4;
    const int r = w >> 1, c = w & 1;

    const int idx = blockIdx.x;
    const int b = idx & 7;
    const int j = idx >> 3;
    const int qt = (j < 32) ? j : 95 - j;
    const int i0 = qt * 32;
    const int nj = (qt >> 1) + 1;

    const unsigned short* qhi = ws;
    const unsigned short* qlo = ws + kMH;
    const unsigned short* khi = ws + 2 * kMH;
    const unsigned short* klo = ws + 3 * kMH;
    const unsigned short* vt  = ws + 4 * kMH;

    // Q frags (A-layout), rows i0 + r*16 + li
    bf16x8 qh[4], ql[4];
    {
        const size_t qoff = ((size_t)(b * kT + i0 + r * 16 + li)) * kH;
#pragma unroll
        for (int kc = 0; kc < 4; ++kc) {
            qh[kc] = *(const bf16x8*)(qhi + qoff + kc * 32 + quad * 8);
            ql[kc] = *(const bf16x8*)(qlo + qoff + kc * 32 + quad * 8);
        }
    }

    f32x4 o[8];
#pragma unroll
    for (int ht = 0; ht < 8; ++ht) o[ht] = (f32x4){0.f, 0.f, 0.f, 0.f};
    float m_i[4] = {-3.0e38f, -3.0e38f, -3.0e38f, -3.0e38f};
    float l_i[4] = {0.f, 0.f, 0.f, 0.f};

    auto stage = [&](int jtile, unsigned short* Kh, unsigned short* Kl) {
        const size_t kgb = ((size_t)(b * kT + jtile * 64)) * kH;
#pragma unroll
        for (int u = 0; u < 4; ++u) {
            const int f = u * 256 + tid;
            const int row = f >> 4, p = f & 15, g = p ^ (row & 15);
            load_lds16(khi + kgb + row * 128 + g * 8, Kh + f * 8);
            load_lds16(klo + kgb + row * 128 + g * 8, Kl + f * 8);
        }
    };

    auto compute = [&](int jtile, const unsigned short* Kh,
                       const unsigned short* Kl,
                       unsigned short* KhN, unsigned short* KlN) {
        // V B-frags straight from global (contiguous 16B), before next DMA
        bf16x8 vf[8];
#pragma unroll
        for (int ht = 0; ht < 8; ++ht)
            vf[ht] = *(const bf16x8*)(vt + (size_t)(b * kH + ht * 16 + li) * kT +
                                      jtile * 64 + c * 32 + quad * 8);
        __builtin_amdgcn_sched_barrier(0);
        if (jtile + 1 < nj) stage(jtile + 1, KhN, KlN);

        // S = Q K^T (split-bf16), 32 cols per wave
        f32x4 s[2];
        s[0] = (f32x4){0.f, 0.f, 0.f, 0.f};
        s[1] = (f32x4){0.f, 0.f, 0.f, 0.f};
#pragma unroll
        for (int nt = 0; nt < 2; ++nt) {
            const int t = c * 32 + nt * 16 + li;
#pragma unroll
            for (int kc = 0; kc < 4; ++kc) {
                const int pos = (kc * 4 + quad) ^ li;
                const bf16x8 kh = *(const bf16x8*)(Kh + t * 128 + pos * 8);
                const bf16x8 kl = *(const bf16x8*)(Kl + t * 128 + pos * 8);
                s[nt] = __builtin_amdgcn_mfma_f32_16x16x32_bf16(qh[kc], kh, s[nt], 0, 0, 0);
                s[nt] = __builtin_amdgcn_mfma_f32_16x16x32_bf16(ql[kc], kh, s[nt], 0, 0, 0);
                s[nt] = __builtin_amdgcn_mfma_f32_16x16x32_bf16(qh[kc], kl, s[nt], 0, 0, 0);
            }
        }
        if (jtile == nj - 1) {
            const int grow0 = i0 + r * 16 + quad * 4;
            const int gcol0 = jtile * 64 + c * 32 + li;
#pragma unroll
            for (int nt = 0; nt < 2; ++nt)
#pragma unroll
                for (int reg = 0; reg < 4; ++reg)
                    if (gcol0 + nt * 16 > grow0 + reg) s[nt][reg] = -3.0e38f;
        }
        // online softmax (rows = quad*4+reg; reduce over li)
        float alpha[4];
#pragma unroll
        for (int reg = 0; reg < 4; ++reg) {
            float mr = fmaxf(s[0][reg], s[1][reg]);
            mr = fmaxf(mr, __shfl_xor(mr, 1));
            mr = fmaxf(mr, __shfl_xor(mr, 2));
            mr = fmaxf(mr, __shfl_xor(mr, 4));
            mr = fmaxf(mr, __shfl_xor(mr, 8));
            const float mn = fmaxf(m_i[reg], mr);
            alpha[reg] = __expf(m_i[reg] - mn);
            m_i[reg] = mn;
            const float p0 = __expf(s[0][reg] - mn);
            const float p1 = __expf(s[1][reg] - mn);
            s[0][reg] = p0; s[1][reg] = p1;
            float rs = p0 + p1;
            rs += __shfl_xor(rs, 1);
            rs += __shfl_xor(rs, 2);
            rs += __shfl_xor(rs, 4);
            rs += __shfl_xor(rs, 8);
            l_i[reg] = l_i[reg] * alpha[reg] + rs;
        }
        const f32x4 av = {alpha[0], alpha[1], alpha[2], alpha[3]};
#pragma unroll
        for (int ht = 0; ht < 8; ++ht) o[ht] *= av;
        // P -> per-wave LDS (C-layout) -> A-frag
#pragma unroll
        for (int nt = 0; nt < 2; ++nt)
#pragma unroll
            for (int reg = 0; reg < 4; ++reg)
                Ps[w][quad * 4 + reg][nt * 16 + li] = f2bf_rne(s[nt][reg]);
        const bf16x8 pf = *(const bf16x8*)&Ps[w][li][quad * 8];
#pragma unroll
        for (int ht = 0; ht < 8; ++ht)
            o[ht] = __builtin_amdgcn_mfma_f32_16x16x32_bf16(pf, vf[ht], o[ht], 0, 0, 0);
    };

    stage(0, Kh0, Kl0);
    int jt = 0;
    while (true) {
        WAIT_VM0();
        RAW_BARRIER();
        compute(jt, Kh0, Kl0, Kh1, Kl1);
        if (++jt >= nj) break;
        WAIT_VM0();
        RAW_BARRIER();
        compute(jt, Kh1, Kl1, Kh0, Kl0);
        if (++jt >= nj) break;
    }

    // ---- merge the two c-halves (flash-decoding combine) ----
    __syncthreads();
#pragma unroll
    for (int reg = 0; reg < 4; ++reg) {
        Ml[r][c][0][quad * 4 + reg] = m_i[reg];
        Ml[r][c][1][quad * 4 + reg] = l_i[reg];
    }
    __syncthreads();
    float a_self[4], linv[4];
#pragma unroll
    for (int reg = 0; reg < 4; ++reg) {
        const float mo = Ml[r][c ^ 1][0][quad * 4 + reg];
        const float lo_ = Ml[r][c ^ 1][1][quad * 4 + reg];
        const float mm = fmaxf(m_i[reg], mo);
        a_self[reg] = __expf(m_i[reg] - mm);
        const float a_oth = __expf(mo - mm);
        linv[reg] = 1.0f / (l_i[reg] * a_self[reg] + lo_ * a_oth);
    }
    if (c == 1) {
#pragma unroll
        for (int ht = 0; ht < 8; ++ht)
#pragma unroll
            for (int reg = 0; reg < 4; ++reg)
                Os[r][quad * 4 + reg][ht * 16 + li] =
                    f2bf_rne(o[ht][reg] * a_self[reg]);
    }
    __syncthreads();
    if (c == 0) {
#pragma unroll
        for (int ht = 0; ht < 8; ++ht)
#pragma unroll
            for (int reg = 0; reg < 4; ++reg) {
                const float v = o[ht][reg] * a_self[reg] +
                                bf2f(Os[r][quad * 4 + reg][ht * 16 + li]);
                out[(size_t)(b * kT + i0 + r * 16 + quad * 4 + reg) * kH +
                    ht * 16 + li] = v * linv[reg];
            }
    }
}

// ---------------------------------------------------------------------------
extern "C" void kernel_launch(void* const* d_in, const int* in_sizes, int n_in,
                              void* d_out, int out_size, void* d_ws, size_t ws_size,
                              hipStream_t stream) {
    // setup_inputs order: x, Wk, Wq, Wv
    const float* x  = (const float*)d_in[0];
    const float* Wk = (const float*)d_in[1];
    const float* Wq = (const float*)d_in[2];
    const float* Wv = (const float*)d_in[3];
    unsigned short* ws = (unsigned short*)d_ws;
    float* out = (float*)d_out;

    hipLaunchKernelGGL(prep_w, dim3(128, 3), dim3(256), 0, stream, Wk, Wq, Wv, ws);
    hipLaunchKernelGGL(qkv_mfma, dim3(512), dim3(256), 0, stream, x, ws);
    hipLaunchKernelGGL(attn_mfma, dim3(512), dim3(256), 0, stream,
                       (const unsigned short*)ws, out);
}

// Round 5
// 199.204 us; speedup vs baseline: 4.3805x; 1.0875x over previous
//
#include <hip/hip_runtime.h>

// Problem constants: B=8, T=2048, C=1024, H=128
constexpr int kB = 8;
constexpr int kT = 2048;
constexpr int kC = 1024;
constexpr int kH = 128;
constexpr int kM = kB * kT;                 // 16384 rows
constexpr size_t kMH = (size_t)kM * kH;     // 2,097,152
constexpr size_t kWH = (size_t)kC * kH;     // 131,072

typedef __attribute__((ext_vector_type(8))) short bf16x8;   // MFMA A/B frag
typedef __attribute__((ext_vector_type(4))) float f32x4;    // MFMA C/D frag

// ws layout (ushort): qhi | qlo | khi | klo | vT[B][H][T] | 6x WT (hi/lo per mat)

__device__ inline unsigned short f2bf_rne(float f) {
    union { float f; unsigned int u; } x; x.f = f;
    unsigned int r = x.u + 0x7fff + ((x.u >> 16) & 1);
    return (unsigned short)(r >> 16);
}
__device__ inline float bf2f(unsigned short h) {
    union { float f; unsigned int u; } x; x.u = ((unsigned int)h) << 16;
    return x.f;
}
__device__ inline unsigned int pack_hi2(float a, float b) {  // trunc-hi16 pack
    return __builtin_amdgcn_perm(__float_as_uint(b), __float_as_uint(a),
                                 0x07060302u);
}
__device__ inline float hi_part(float v) {
    return __uint_as_float(__float_as_uint(v) & 0xffff0000u);
}
__device__ inline void load_lds16(const unsigned short* g, unsigned short* l) {
    __builtin_amdgcn_global_load_lds(
        (const __attribute__((address_space(1))) unsigned int*)g,
        (__attribute__((address_space(3))) unsigned int*)l, 16, 0, 0);
}

// ---------------------------------------------------------------------------
// Kernel 0: split + transpose weights -> WT_hi (RNE) / WT_lo [H][C] bf16.
// ---------------------------------------------------------------------------
__global__ __launch_bounds__(256) void prep_w(
    const float* __restrict__ Wk, const float* __restrict__ Wq,
    const float* __restrict__ Wv, unsigned short* __restrict__ ws)
{
    const int h = blockIdx.x;
    const int mat = blockIdx.y;
    const float* W = (mat == 0) ? Wq : (mat == 1) ? Wk : Wv;
    unsigned short* hi = ws + 5 * kMH + (size_t)(mat * 2) * kWH;
    unsigned short* lo = hi + kWH;

    const int k0 = threadIdx.x * 4;
    unsigned short hv[4], lv[4];
#pragma unroll
    for (int j = 0; j < 4; ++j) {
        const float f = W[(size_t)(k0 + j) * kH + h];
        hv[j] = f2bf_rne(f);
        lv[j] = f2bf_rne(f - bf2f(hv[j]));
    }
    *(uint2*)&hi[(size_t)h * kC + k0] =
        make_uint2(((unsigned)hv[1] << 16) | hv[0], ((unsigned)hv[3] << 16) | hv[2]);
    *(uint2*)&lo[(size_t)h * kC + k0] =
        make_uint2(((unsigned)lv[1] << 16) | lv[0], ((unsigned)lv[3] << 16) | lv[2]);
}

// ---------------------------------------------------------------------------
// Kernel 1: QKV projection. 768 blocks, M=64 each:
//   idx<256: q (split-bf16)   256..511: k (split-bf16)   >=512: v (single RNE)
// CU i hosts q(i), k(i+256), v(i+512): same m0 -> x rows hit L1/L2 3x.
// 3 blocks/CU, LDS 25.6 KB, K-step 32.
// ---------------------------------------------------------------------------
__global__ __launch_bounds__(256) void qkv_mfma(
    const float* __restrict__ x, unsigned short* __restrict__ ws)
{
    __shared__ __align__(16) unsigned short Ah[64][36];
    __shared__ __align__(16) unsigned short Al[64][36];
    __shared__ __align__(16) unsigned short Bh[128 * 32];
    __shared__ __align__(16) unsigned short Bl[128 * 32];

    const int idx = blockIdx.x;
    const int mat = idx >> 8;               // 0=q, 1=k, 2=v
    const int m0 = (idx & 255) * 64;
    const unsigned short* wThi = ws + 5 * kMH + (size_t)(mat * 2) * kWH;
    const unsigned short* wTlo = wThi + kWH;

    const int tid = threadIdx.x;
    const int w = tid >> 6, lane = tid & 63;
    const int li = lane & 15, quad = lane >> 4;
    const int wm = w >> 1, wn = w & 1;      // row-32-half, col-64-half

    const int ar = tid >> 2;                // A-stage row 0..63
    const int ac = (tid & 3) * 8;           // A-stage col

    f32x4 acc[2][4];
#pragma unroll
    for (int i = 0; i < 2; ++i)
#pragma unroll
        for (int j = 0; j < 4; ++j) acc[i][j] = (f32x4){0.f, 0.f, 0.f, 0.f};

    if (mat <= 1) {
        // -------- q / k : split-bf16 (3 MFMAs per product) --------
        for (int kt = 0; kt < kC; kt += 32) {
            if (kt) __syncthreads();
            // A: x[64][32] fp32 -> trunc hi/lo bf16
            {
                const float4 x0 = *(const float4*)(x + (size_t)(m0 + ar) * kC + kt + ac);
                const float4 x1 = *(const float4*)(x + (size_t)(m0 + ar) * kC + kt + ac + 4);
                *(uint2*)&Ah[ar][ac] = make_uint2(pack_hi2(x0.x, x0.y), pack_hi2(x0.z, x0.w));
                *(uint2*)&Ah[ar][ac + 4] = make_uint2(pack_hi2(x1.x, x1.y), pack_hi2(x1.z, x1.w));
                const float l0 = x0.x - hi_part(x0.x), l1 = x0.y - hi_part(x0.y);
                const float l2 = x0.z - hi_part(x0.z), l3 = x0.w - hi_part(x0.w);
                const float l4 = x1.x - hi_part(x1.x), l5 = x1.y - hi_part(x1.y);
                const float l6 = x1.z - hi_part(x1.z), l7 = x1.w - hi_part(x1.w);
                *(uint2*)&Al[ar][ac] = make_uint2(pack_hi2(l0, l1), pack_hi2(l2, l3));
                *(uint2*)&Al[ar][ac + 4] = make_uint2(pack_hi2(l4, l5), pack_hi2(l6, l7));
            }
            // B: DMA [128][32] hi+lo; LDS granule p of row r holds global p^(r&3)
#pragma unroll
            for (int u = 0; u < 2; ++u) {
                const int f = u * 256 + tid;
                const int row = f >> 2, g = (f & 3) ^ ((f >> 2) & 3);
                load_lds16(wThi + (size_t)row * kC + kt + g * 8, Bh + f * 8);
                load_lds16(wTlo + (size_t)row * kC + kt + g * 8, Bl + f * 8);
            }
            __syncthreads();

            bf16x8 ah[2], al[2];
#pragma unroll
            for (int mt = 0; mt < 2; ++mt) {
                ah[mt] = *(const bf16x8*)&Ah[wm * 32 + mt * 16 + li][quad * 8];
                al[mt] = *(const bf16x8*)&Al[wm * 32 + mt * 16 + li][quad * 8];
            }
#pragma unroll
            for (int nt = 0; nt < 4; ++nt) {
                const int row = wn * 64 + nt * 16 + li;
                const int pos = quad ^ (row & 3);
                const bf16x8 bh = *(const bf16x8*)&Bh[row * 32 + pos * 8];
                const bf16x8 bl = *(const bf16x8*)&Bl[row * 32 + pos * 8];
#pragma unroll
                for (int mt = 0; mt < 2; ++mt) {
                    acc[mt][nt] = __builtin_amdgcn_mfma_f32_16x16x32_bf16(ah[mt], bh, acc[mt][nt], 0, 0, 0);
                    acc[mt][nt] = __builtin_amdgcn_mfma_f32_16x16x32_bf16(al[mt], bh, acc[mt][nt], 0, 0, 0);
                    acc[mt][nt] = __builtin_amdgcn_mfma_f32_16x16x32_bf16(ah[mt], bl, acc[mt][nt], 0, 0, 0);
                }
            }
        }
        // epilogue: hi/lo split [M][H] (q scaled by 32)
        unsigned short* hip_ = ws + (size_t)(mat * 2) * kMH;
        unsigned short* lop  = hip_ + kMH;
        const float sc = (mat == 0) ? 32.0f : 1.0f;
#pragma unroll
        for (int mt = 0; mt < 2; ++mt)
#pragma unroll
            for (int nt = 0; nt < 4; ++nt) {
                const int col = wn * 64 + nt * 16 + li;
#pragma unroll
                for (int reg = 0; reg < 4; ++reg) {
                    const int row = m0 + wm * 32 + mt * 16 + quad * 4 + reg;
                    const float v = acc[mt][nt][reg] * sc;
                    hip_[(size_t)row * kH + col] = (unsigned short)(__float_as_uint(v) >> 16);
                    lop[(size_t)row * kH + col] =
                        (unsigned short)(__float_as_uint(v - hi_part(v)) >> 16);
                }
            }
    } else {
        // -------- v : single RNE-bf16 product --------
        for (int kt = 0; kt < kC; kt += 32) {
            if (kt) __syncthreads();
            {
                const float4 x0 = *(const float4*)(x + (size_t)(m0 + ar) * kC + kt + ac);
                const float4 x1 = *(const float4*)(x + (size_t)(m0 + ar) * kC + kt + ac + 4);
                unsigned short h0 = f2bf_rne(x0.x), h1 = f2bf_rne(x0.y);
                unsigned short h2 = f2bf_rne(x0.z), h3 = f2bf_rne(x0.w);
                unsigned short h4 = f2bf_rne(x1.x), h5 = f2bf_rne(x1.y);
                unsigned short h6 = f2bf_rne(x1.z), h7 = f2bf_rne(x1.w);
                *(uint2*)&Ah[ar][ac] =
                    make_uint2(((unsigned)h1 << 16) | h0, ((unsigned)h3 << 16) | h2);
                *(uint2*)&Ah[ar][ac + 4] =
                    make_uint2(((unsigned)h5 << 16) | h4, ((unsigned)h7 << 16) | h6);
            }
#pragma unroll
            for (int u = 0; u < 2; ++u) {
                const int f = u * 256 + tid;
                const int row = f >> 2, g = (f & 3) ^ ((f >> 2) & 3);
                load_lds16(wThi + (size_t)row * kC + kt + g * 8, Bh + f * 8);
            }
            __syncthreads();

            bf16x8 a[2];
#pragma unroll
            for (int mt = 0; mt < 2; ++mt)
                a[mt] = *(const bf16x8*)&Ah[wm * 32 + mt * 16 + li][quad * 8];
#pragma unroll
            for (int nt = 0; nt < 4; ++nt) {
                const int row = wn * 64 + nt * 16 + li;
                const int pos = quad ^ (row & 3);
                const bf16x8 bh = *(const bf16x8*)&Bh[row * 32 + pos * 8];
#pragma unroll
                for (int mt = 0; mt < 2; ++mt)
                    acc[mt][nt] = __builtin_amdgcn_mfma_f32_16x16x32_bf16(a[mt], bh, acc[mt][nt], 0, 0, 0);
            }
        }
        // epilogue: vT [B][H][T] bf16 RNE
        unsigned short* vt = ws + 4 * kMH;
        const int bb = m0 >> 11;
        const int t00 = (m0 & (kT - 1)) + wm * 32;
#pragma unroll
        for (int mt = 0; mt < 2; ++mt)
#pragma unroll
            for (int nt = 0; nt < 4; ++nt) {
                const int h = wn * 64 + nt * 16 + li;
                ushort4 pk;
                pk.x = f2bf_rne(acc[mt][nt][0]);
                pk.y = f2bf_rne(acc[mt][nt][1]);
                pk.z = f2bf_rne(acc[mt][nt][2]);
                pk.w = f2bf_rne(acc[mt][nt][3]);
                const int t0 = t00 + mt * 16 + quad * 4;
                *(ushort4*)&vt[((size_t)(bb * kH + h)) * kT + t0] = pk;
            }
    }
}

// ---------------------------------------------------------------------------
// Kernel 2: flash attention, barrier-free hot loop.
// 512 blocks (b=idx&7 -> XCD-local K/V in L2) x 4 INDEPENDENT waves.
// Wave w: all 32 Q-rows (2 m-frags), K-chunks jc == w (mod 4), 32 cols each.
// K/V B-frags read DIRECTLY from global (contiguous 16B/lane, L2-resident).
// Private online softmax per wave; 4-way (m,l,O) merge once at the end.
// Pairing qt <-> 63-qt keeps per-CU totals equal; no intra-loop syncs mean
// an early-finishing co-tenant costs nothing.
// ---------------------------------------------------------------------------
__global__ __launch_bounds__(256, 2) void attn_mfma(
    const unsigned short* __restrict__ ws, float* __restrict__ out)
{
    __shared__ __align__(16) unsigned short Ps[4][2][16][40];
    __shared__ __align__(16) float Ml[4][32][2];
    __shared__ __align__(16) float Obuf[3][32][128];

    const int tid = threadIdx.x;
    const int w = tid >> 6, lane = tid & 63;
    const int li = lane & 15, quad = lane >> 4;

    const int idx = blockIdx.x;
    const int b = idx & 7;
    const int j = idx >> 3;
    const int qt = (j < 32) ? j : 95 - j;   // pair qt with 63-qt per CU
    const int i0 = qt * 32;
    const int nc = qt + 1;                  // 32-col causal chunks

    const unsigned short* qhi = ws;
    const unsigned short* qlo = ws + kMH;
    const unsigned short* khi = ws + 2 * kMH;
    const unsigned short* klo = ws + 3 * kMH;
    const unsigned short* vt  = ws + 4 * kMH;

    // Q frags (A-layout), 2 m-tiles
    bf16x8 qh[2][4], ql[2][4];
#pragma unroll
    for (int mi = 0; mi < 2; ++mi) {
        const size_t qoff = ((size_t)(b * kT + i0 + mi * 16 + li)) * kH;
#pragma unroll
        for (int kc = 0; kc < 4; ++kc) {
            qh[mi][kc] = *(const bf16x8*)(qhi + qoff + kc * 32 + quad * 8);
            ql[mi][kc] = *(const bf16x8*)(qlo + qoff + kc * 32 + quad * 8);
        }
    }

    f32x4 o[2][8];
#pragma unroll
    for (int mi = 0; mi < 2; ++mi)
#pragma unroll
        for (int ht = 0; ht < 8; ++ht) o[mi][ht] = (f32x4){0.f, 0.f, 0.f, 0.f};
    float m_i[2][4], l_i[2][4];
#pragma unroll
    for (int mi = 0; mi < 2; ++mi)
#pragma unroll
        for (int reg = 0; reg < 4; ++reg) { m_i[mi][reg] = -3.0e38f; l_i[mi][reg] = 0.f; }

    for (int jc = w; jc < nc; jc += 4) {
        const int t0 = jc * 32;
        // V B-frags (used at the end -> latency covered by QK+softmax)
        bf16x8 vf[8];
#pragma unroll
        for (int ht = 0; ht < 8; ++ht)
            vf[ht] = *(const bf16x8*)(vt + (size_t)(b * kH + ht * 16 + li) * kT +
                                      t0 + quad * 8);
        // S = Q K^T (split-bf16)
        f32x4 s[2][2];
#pragma unroll
        for (int mi = 0; mi < 2; ++mi)
#pragma unroll
            for (int nt = 0; nt < 2; ++nt) s[mi][nt] = (f32x4){0.f, 0.f, 0.f, 0.f};
#pragma unroll
        for (int kc = 0; kc < 4; ++kc) {
            bf16x8 kh[2], kl[2];
#pragma unroll
            for (int nt = 0; nt < 2; ++nt) {
                const size_t ka =
                    ((size_t)(b * kT + t0 + nt * 16 + li)) * kH + kc * 32 + quad * 8;
                kh[nt] = *(const bf16x8*)(khi + ka);
                kl[nt] = *(const bf16x8*)(klo + ka);
            }
#pragma unroll
            for (int mi = 0; mi < 2; ++mi)
#pragma unroll
                for (int nt = 0; nt < 2; ++nt) {
                    s[mi][nt] = __builtin_amdgcn_mfma_f32_16x16x32_bf16(qh[mi][kc], kh[nt], s[mi][nt], 0, 0, 0);
                    s[mi][nt] = __builtin_amdgcn_mfma_f32_16x16x32_bf16(ql[mi][kc], kh[nt], s[mi][nt], 0, 0, 0);
                    s[mi][nt] = __builtin_amdgcn_mfma_f32_16x16x32_bf16(qh[mi][kc], kl[nt], s[mi][nt], 0, 0, 0);
                }
        }
        // causal mask (diagonal chunk only)
        if (jc == qt) {
#pragma unroll
            for (int mi = 0; mi < 2; ++mi) {
                const int grow0 = i0 + mi * 16 + quad * 4;
#pragma unroll
                for (int nt = 0; nt < 2; ++nt) {
                    const int gcol = t0 + nt * 16 + li;
#pragma unroll
                    for (int reg = 0; reg < 4; ++reg)
                        if (gcol > grow0 + reg) s[mi][nt][reg] = -3.0e38f;
                }
            }
        }
        // online softmax
#pragma unroll
        for (int mi = 0; mi < 2; ++mi) {
            float alpha[4];
#pragma unroll
            for (int reg = 0; reg < 4; ++reg) {
                float mr = fmaxf(s[mi][0][reg], s[mi][1][reg]);
                mr = fmaxf(mr, __shfl_xor(mr, 1));
                mr = fmaxf(mr, __shfl_xor(mr, 2));
                mr = fmaxf(mr, __shfl_xor(mr, 4));
                mr = fmaxf(mr, __shfl_xor(mr, 8));
                const float mn = fmaxf(m_i[mi][reg], mr);
                alpha[reg] = __expf(m_i[mi][reg] - mn);
                m_i[mi][reg] = mn;
                const float p0 = __expf(s[mi][0][reg] - mn);
                const float p1 = __expf(s[mi][1][reg] - mn);
                s[mi][0][reg] = p0; s[mi][1][reg] = p1;
                float rs = p0 + p1;
                rs += __shfl_xor(rs, 1);
                rs += __shfl_xor(rs, 2);
                rs += __shfl_xor(rs, 4);
                rs += __shfl_xor(rs, 8);
                l_i[mi][reg] = l_i[mi][reg] * alpha[reg] + rs;
            }
            const f32x4 av = {alpha[0], alpha[1], alpha[2], alpha[3]};
#pragma unroll
            for (int ht = 0; ht < 8; ++ht) o[mi][ht] *= av;
            // P -> per-wave LDS (C-layout) -> A-frag (same-wave, no barrier)
#pragma unroll
            for (int nt = 0; nt < 2; ++nt)
#pragma unroll
                for (int reg = 0; reg < 4; ++reg)
                    Ps[w][mi][quad * 4 + reg][nt * 16 + li] = f2bf_rne(s[mi][nt][reg]);
        }
#pragma unroll
        for (int mi = 0; mi < 2; ++mi) {
            const bf16x8 pf = *(const bf16x8*)&Ps[w][mi][li][quad * 8];
#pragma unroll
            for (int ht = 0; ht < 8; ++ht)
                o[mi][ht] = __builtin_amdgcn_mfma_f32_16x16x32_bf16(pf, vf[ht], o[mi][ht], 0, 0, 0);
        }
    }

    // ---- 4-way merge across waves ----
    if (li == 0) {
#pragma unroll
        for (int mi = 0; mi < 2; ++mi)
#pragma unroll
            for (int reg = 0; reg < 4; ++reg) {
                Ml[w][mi * 16 + quad * 4 + reg][0] = m_i[mi][reg];
                Ml[w][mi * 16 + quad * 4 + reg][1] = l_i[mi][reg];
            }
    }
    __syncthreads();
    float a_self[2][4], linv[2][4];
#pragma unroll
    for (int mi = 0; mi < 2; ++mi)
#pragma unroll
        for (int reg = 0; reg < 4; ++reg) {
            const int row = mi * 16 + quad * 4 + reg;
            const float m0_ = Ml[0][row][0], m1 = Ml[1][row][0];
            const float m2 = Ml[2][row][0], m3 = Ml[3][row][0];
            const float ms = fmaxf(fmaxf(m0_, m1), fmaxf(m2, m3));
            const float L = Ml[0][row][1] * __expf(m0_ - ms) +
                            Ml[1][row][1] * __expf(m1 - ms) +
                            Ml[2][row][1] * __expf(m2 - ms) +
                            Ml[3][row][1] * __expf(m3 - ms);
            a_self[mi][reg] = __expf(m_i[mi][reg] - ms);
            linv[mi][reg] = 1.0f / L;
        }
    if (w) {
#pragma unroll
        for (int mi = 0; mi < 2; ++mi)
#pragma unroll
            for (int ht = 0; ht < 8; ++ht)
#pragma unroll
                for (int reg = 0; reg < 4; ++reg)
                    Obuf[w - 1][mi * 16 + quad * 4 + reg][ht * 16 + li] =
                        o[mi][ht][reg] * a_self[mi][reg];
    }
    __syncthreads();
    if (w == 0) {
#pragma unroll
        for (int mi = 0; mi < 2; ++mi)
#pragma unroll
            for (int ht = 0; ht < 8; ++ht)
#pragma unroll
                for (int reg = 0; reg < 4; ++reg) {
                    const int row = mi * 16 + quad * 4 + reg;
                    const int col = ht * 16 + li;
                    const float v = o[mi][ht][reg] * a_self[mi][reg] +
                                    Obuf[0][row][col] + Obuf[1][row][col] +
                                    Obuf[2][row][col];
                    out[(size_t)(b * kT + i0 + row) * kH + col] = v * linv[mi][reg];
                }
    }
}

// ---------------------------------------------------------------------------
extern "C" void kernel_launch(void* const* d_in, const int* in_sizes, int n_in,
                              void* d_out, int out_size, void* d_ws, size_t ws_size,
                              hipStream_t stream) {
    // setup_inputs order: x, Wk, Wq, Wv
    const float* x  = (const float*)d_in[0];
    const float* Wk = (const float*)d_in[1];
    const float* Wq = (const float*)d_in[2];
    const float* Wv = (const float*)d_in[3];
    unsigned short* ws = (unsigned short*)d_ws;
    float* out = (float*)d_out;

    hipLaunchKernelGGL(prep_w, dim3(128, 3), dim3(256), 0, stream, Wk, Wq, Wv, ws);
    hipLaunchKernelGGL(qkv_mfma, dim3(768), dim3(256), 0, stream, x, ws);
    hipLaunchKernelGGL(attn_mfma, dim3(512), dim3(256), 0, stream,
                       (const unsigned short*)ws, out);
}